// Round 11
// baseline (572.577 us; speedup 1.0000x reference)
//
#include <hip/hip_runtime.h>
#include <hip/hip_bf16.h>

#define B_ 2
#define N_ 384
#define D_ 128
#define LAT_ 256
#define NPOS_ 33
#define ROWS_ (B_*N_)   // 768
#define NT_ 64          // n-rows per attn iteration
#define ITERS_ (N_/NT_) // 6

typedef __attribute__((ext_vector_type(8))) short bf16x8;
typedef __attribute__((ext_vector_type(4))) float f32x4;

#define MFMA(a,b,c) __builtin_amdgcn_mfma_f32_16x16x32_bf16((a),(b),(c),0,0,0)

__device__ __forceinline__ unsigned short f2bf(float x) {
    unsigned int u = __float_as_uint(x);
    u += 0x7FFFu + ((u >> 16) & 1u);   // round-to-nearest-even
    return (unsigned short)(u >> 16);
}
__device__ __forceinline__ float bf2f(unsigned short u) {
    return __uint_as_float(((unsigned int)u) << 16);
}

__device__ __forceinline__ float bn_apply(float x, const float* stats, const float* gam,
                                          const float* bet, int d) {
    float s  = stats[d], sq = stats[128 + d];
    float mean = s * (1.f/ROWS_);
    float var  = sq * (1.f/ROWS_) - mean*mean;
    return (x - mean) * rsqrtf(var + 1e-5f) * gam[d] + bet[d];
}

// ---------------- fused prep: fprep | psi | enc | Wqg/Wkg, by blockIdx range ----------------
// [0,192)    : gF[n][64] bf16 swizzled features
// [192,243)  : psi[layer][e][34] = Wg1@Wpe (col33 = Wg1@bpe), 2 cols/block
// [243,627)  : enc f = feats*W + b
// [627,1011) : Wqg = Wg1@Wq, Wkg = Wg1@Wk (2 cols/block)
#define PB_FPREP 192
#define PB_PSI   (PB_FPREP + 51)
#define PB_ENC   (PB_PSI + 384)
#define PB_WQG   (PB_ENC + 384)
__global__ __launch_bounds__(256) void prep_kernel(
    const float* __restrict__ xyz, const float* __restrict__ feats,
    const float* __restrict__ enc_W, const float* __restrict__ enc_b,
    const float* __restrict__ Wg1, const float* __restrict__ Wpe, const float* __restrict__ bpe,
    const float* __restrict__ Wq, const float* __restrict__ Wk,
    unsigned short* __restrict__ gF, float* __restrict__ psi,
    float* __restrict__ wqg, float* __restrict__ wkg, float* __restrict__ f)
{
    const int blk = blockIdx.x, t = threadIdx.x;
    if (blk < PB_FPREP) {
        int i = blk*256 + t;               // over ROWS_*64
        int n = i >> 6, q = i & 63;
        float val;
        if (q == 0) val = 1.f;
        else if (q < 4) val = 4.f*xyz[n*3 + (q-1)];
        else if (q < 34) {
            int u = q-4, fi = u/6, rem = u - fi*6, j = rem >> 1;
            const float fr = fi==0?1.f:(fi==1?8.75f:(fi==2?16.5f:(fi==3?24.25f:32.f)));
            float a = fr*4.f*xyz[n*3+j];
            val = (rem & 1) ? __sinf(a) : __cosf(a);
        } else val = 0.f;
        gF[n*64 + (q ^ ((n & 7) << 3))] = f2bf(val);
    } else if (blk < PB_PSI) {
        __shared__ float col2[2][D_];
        const int colid = (blk - PB_FPREP)*2 + (t >> 7);   // 0..101
        const int layer = colid / 34, p = colid - layer*34;
        const int e = t & 127, half = t >> 7;
        col2[half][e] = (p < NPOS_) ? Wpe[layer*D_*NPOS_ + e*NPOS_ + p]
                                    : bpe[layer*D_ + e];
        __syncthreads();
        const float* wg1 = Wg1 + layer*D_*D_;
        float acc = 0.f;
        #pragma unroll 4
        for (int d4 = 0; d4 < 32; ++d4) {
            float4 w = *(const float4*)(wg1 + e*D_ + d4*4);
            acc += w.x*col2[half][d4*4] + w.y*col2[half][d4*4+1]
                 + w.z*col2[half][d4*4+2] + w.w*col2[half][d4*4+3];
        }
        psi[layer*D_*34 + e*34 + p] = acc;
    } else if (blk < PB_ENC) {
        int i = (blk - PB_PSI)*256 + t;    // over ROWS_*D_
        int r = i >> 7, d = i & 127;
        f[i] = feats[r]*enc_W[d] + enc_b[d];
    } else {
        __shared__ float col2[2][D_];
        const int colid = (blk - PB_ENC)*2 + (t >> 7);     // 0..767
        const int layer = colid >> 8, rem = colid & 255;
        const int mat = rem >> 7, ecol = rem & 127;
        const int e = t & 127, half = t >> 7;
        const float* Wsrc = mat ? Wk : Wq;
        col2[half][e] = Wsrc[layer*D_*D_ + e*D_ + ecol];
        __syncthreads();
        const float* wg1 = Wg1 + layer*D_*D_;
        float acc = 0.f;
        #pragma unroll 4
        for (int d4 = 0; d4 < 32; ++d4) {
            float4 w = *(const float4*)(wg1 + e*D_ + d4*4);
            acc += w.x*col2[half][d4*4] + w.y*col2[half][d4*4+1]
                 + w.z*col2[half][d4*4+2] + w.w*col2[half][d4*4+3];
        }
        float* dst = mat ? wkg : wqg;
        dst[layer*D_*D_ + e*D_ + ecol] = acc;
    }
}

// ---------------- qkv3: single-phase, 1 row/block: v, hb = f@Wqg^T+bg1, kw = f@Wkg^T ----------------
__global__ __launch_bounds__(128) void qkv3_kernel(const float* __restrict__ graw,
    const float* __restrict__ stats, const float* __restrict__ gam, const float* __restrict__ bet,
    int use_stats,
    const float* __restrict__ Wv, const float* __restrict__ Wqg, const float* __restrict__ Wkg,
    const float* __restrict__ bg1,
    float* __restrict__ hb, unsigned short* __restrict__ kw16, unsigned short* __restrict__ v16)
{
    __shared__ float row[D_];
    const int r = blockIdx.x, d = threadIdx.x;
    float x = graw[r*D_ + d];
    if (use_stats) x = bn_apply(x, stats, gam, bet, d);
    row[d] = x;
    __syncthreads();
    float av = 0.f, ah = bg1[d], ak = 0.f;
    #pragma unroll 4
    for (int e4 = 0; e4 < D_/4; ++e4) {
        float4 wv = *(const float4*)(Wv  + d*D_ + e4*4);
        float4 wh = *(const float4*)(Wqg + d*D_ + e4*4);
        float4 wk = *(const float4*)(Wkg + d*D_ + e4*4);
        float4 xx = *(const float4*)&row[e4*4];
        av += wv.x*xx.x + wv.y*xx.y + wv.z*xx.z + wv.w*xx.w;
        ah += wh.x*xx.x + wh.y*xx.y + wh.z*xx.z + wh.w*xx.w;
        ak += wk.x*xx.x + wk.y*xx.y + wk.z*xx.z + wk.w*xx.w;
    }
    v16[r*D_ + d]  = f2bf(av);
    hb[r*D_ + d]   = ah;
    kw16[r*D_ + d] = f2bf(ak);
}

// ---------------- MFMA attention (unchanged from round 10) ----------------
__global__ __launch_bounds__(512) void attn_mfma_kernel(
    const float* __restrict__ xyz, const float* __restrict__ graw,
    const float* __restrict__ stats_in, const float* __restrict__ gam_in,
    const float* __restrict__ bet_in, int use_stats,
    const float* __restrict__ hbb,
    const unsigned short* __restrict__ kwb, const unsigned short* __restrict__ vb,
    const unsigned short* __restrict__ gF,
    const float* __restrict__ psiL,
    const float* __restrict__ Wpe, const float* __restrict__ bpe,
    const float* __restrict__ Wg2, const float* __restrict__ bg2,
    float* __restrict__ gout, float* __restrict__ stats_out)
{
    __shared__ unsigned short sF[NT_*64];    // bf16 swizzled (8KB)
    __shared__ unsigned short sH[NT_*128];   // bf16 swizzled (16KB)
    __shared__ float sRed[4*128];

    const int t   = threadIdx.x;
    const int w   = t >> 6;
    const int l   = t & 63;
    const int lr  = l & 15;
    const int lg  = l >> 4;
    const int rb2 = w >> 2;
    const int ct0 = (w & 3) * 2;

    const int row  = blockIdx.x;
    const int b    = row / N_;
    const int brow = b * N_;

    uint4 freg = *(const uint4*)(gF + (size_t)brow*64 + t*8);
    unsigned short kw_us[2][2][4];
    unsigned short v_us[2][2][4];
    auto loadKW = [&](int n0) {
        #pragma unroll
        for (int rt = 0; rt < 2; ++rt)
        #pragma unroll
        for (int ct = 0; ct < 2; ++ct) {
            const int d = (ct0 + ct)*16 + lr;
            #pragma unroll
            for (int r = 0; r < 4; ++r) {
                const int rr = rb2*32 + rt*16 + lg*4 + r;
                kw_us[rt][ct][r] = kwb[(brow + n0 + rr)*D_ + d];
            }
        }
    };
    auto loadV = [&](int n0) {
        #pragma unroll
        for (int rt = 0; rt < 2; ++rt)
        #pragma unroll
        for (int ct = 0; ct < 2; ++ct) {
            const int d = (ct0 + ct)*16 + lr;
            #pragma unroll
            for (int r = 0; r < 4; ++r) {
                const int rr = rb2*32 + rt*16 + lg*4 + r;
                v_us[rt][ct][r] = vb[(brow + n0 + rr)*D_ + d];
            }
        }
    };
    loadKW(0);

    bf16x8 bWg2[2][4], bG[2][2], bT[2][2];
    float  hb_c[2], bg2_c[2];

    const float xm0 = 4.f*xyz[row*3+0];
    const float xm1 = 4.f*xyz[row*3+1];
    const float xm2 = 4.f*xyz[row*3+2];

    #pragma unroll
    for (int ct = 0; ct < 2; ++ct) {
        const int dout = (ct0 + ct) * 16 + lr;
        #pragma unroll
        for (int kt = 0; kt < 4; ++kt) {
            const float* p2 = Wg2 + dout * D_ + kt * 32 + lg * 8;
            float4 c0 = *(const float4*)(p2);
            float4 c1 = *(const float4*)(p2 + 4);
            bf16x8 v2;
            v2[0]=(short)f2bf(c0.x); v2[1]=(short)f2bf(c0.y); v2[2]=(short)f2bf(c0.z); v2[3]=(short)f2bf(c0.w);
            v2[4]=(short)f2bf(c1.x); v2[5]=(short)f2bf(c1.y); v2[6]=(short)f2bf(c1.z); v2[7]=(short)f2bf(c1.w);
            bWg2[ct][kt] = v2;
        }
        {
            const float* wrow = Wpe + dout*NPOS_;
            float bias = bpe[dout] + wrow[0]*xm0 + wrow[1]*xm1 + wrow[2]*xm2;
            #pragma unroll
            for (int kt = 0; kt < 2; ++kt) {
                bf16x8 g;
                #pragma unroll
                for (int e = 0; e < 8; ++e) {
                    const int qq = kt*32 + lg*8 + e;
                    float val;
                    if (qq == 0) val = bias;
                    else if (qq < 4) val = -wrow[qq-1];
                    else if (qq < 34) {
                        const int u = qq - 4, fi = u/6, rem = u - fi*6, j = rem >> 1;
                        const float Ws = wrow[3 + 6*fi + j];
                        const float Wc = wrow[3 + 6*fi + 3 + j];
                        const float fr = fi==0?1.f:(fi==1?8.75f:(fi==2?16.5f:(fi==3?24.25f:32.f)));
                        const float am = fr * (j==0?xm0:(j==1?xm1:xm2));
                        const float sm = __sinf(am), cm = __cosf(am);
                        val = (rem & 1) ? (Wc*sm - Ws*cm) : (Ws*sm + Wc*cm);
                    } else val = 0.f;
                    g[e] = (short)f2bf(val);
                }
                bG[ct][kt] = g;
            }
        }
        {
            const float* prow = psiL + dout*34;
            float bias = prow[33] + prow[0]*xm0 + prow[1]*xm1 + prow[2]*xm2;
            #pragma unroll
            for (int kt = 0; kt < 2; ++kt) {
                bf16x8 g;
                #pragma unroll
                for (int e = 0; e < 8; ++e) {
                    const int qq = kt*32 + lg*8 + e;
                    float val;
                    if (qq == 0) val = bias;
                    else if (qq < 4) val = -prow[qq-1];
                    else if (qq < 34) {
                        const int u = qq - 4, fi = u/6, rem = u - fi*6, j = rem >> 1;
                        const float Ws = prow[3 + 6*fi + j];
                        const float Wc = prow[3 + 6*fi + 3 + j];
                        const float fr = fi==0?1.f:(fi==1?8.75f:(fi==2?16.5f:(fi==3?24.25f:32.f)));
                        const float am = fr * (j==0?xm0:(j==1?xm1:xm2));
                        const float sm = __sinf(am), cm = __cosf(am);
                        val = (rem & 1) ? (Wc*sm - Ws*cm) : (Ws*sm + Wc*cm);
                    } else val = 0.f;
                    g[e] = (short)f2bf(val);
                }
                bT[ct][kt] = g;
            }
        }
        hb_c[ct]  = hbb[row*D_ + dout];
        bg2_c[ct] = bg2[dout];
    }

    *(uint4*)&sF[t*8] = freg;
    __syncthreads();

    float res_p[2] = {0.f, 0.f}, s_p[2] = {0.f, 0.f};
    f32x4 pos[2][2];

    for (int it = 0; it < ITERS_; ++it) {
        const int n0 = it * NT_;
        const bool more = (it < ITERS_ - 1);

        loadV(n0);
        if (more) freg = *(const uint4*)(gF + (size_t)(brow + n0 + NT_)*64 + t*8);
        f32x4 hacc[2][2];
        #pragma unroll
        for (int rt = 0; rt < 2; ++rt) {
            const int r16 = rb2*32 + rt*16 + lr;
            const int sw  = (r16 & 7) << 3;
            bf16x8 a0 = *(const bf16x8*)&sF[(r16*64 +  0 + lg*8) ^ sw];
            bf16x8 a1 = *(const bf16x8*)&sF[(r16*64 + 32 + lg*8) ^ sw];
            #pragma unroll
            for (int ct = 0; ct < 2; ++ct) {
                f32x4 z = {0.f,0.f,0.f,0.f};
                hacc[rt][ct] = MFMA(a1, bT[ct][1], MFMA(a0, bT[ct][0], z));
                pos[rt][ct]  = MFMA(a1, bG[ct][1], MFMA(a0, bG[ct][0], z));
            }
        }
        #pragma unroll
        for (int rt = 0; rt < 2; ++rt)
        #pragma unroll
        for (int ct = 0; ct < 2; ++ct) {
            const int d = (ct0 + ct)*16 + lr;
            #pragma unroll
            for (int r = 0; r < 4; ++r) {
                const int rr = rb2*32 + rt*16 + lg*4 + r;
                const float hv = hacc[rt][ct][r] + hb_c[ct] - bf2f(kw_us[rt][ct][r]);
                sH[(rr*128 + d) ^ ((rr & 7) << 3)] = f2bf(fmaxf(hv, 0.f));
            }
        }
        __syncthreads();

        if (more) {
            *(uint4*)&sF[t*8] = freg;
            loadKW(n0 + NT_);
        }
        f32x4 lacc[2][2];
        #pragma unroll
        for (int rt = 0; rt < 2; ++rt) {
            lacc[rt][0] = (f32x4){bg2_c[0], bg2_c[0], bg2_c[0], bg2_c[0]};
            lacc[rt][1] = (f32x4){bg2_c[1], bg2_c[1], bg2_c[1], bg2_c[1]};
            #pragma unroll
            for (int kt = 0; kt < 4; ++kt) {
                const int r16 = rb2*32 + rt*16 + lr;
                const int idx = (r16*128 + kt*32 + lg*8) ^ ((r16 & 7) << 3);
                bf16x8 a = *(const bf16x8*)&sH[idx];
                lacc[rt][0] = MFMA(a, bWg2[0][kt], lacc[rt][0]);
                lacc[rt][1] = MFMA(a, bWg2[1][kt], lacc[rt][1]);
            }
        }
        #pragma unroll
        for (int rt = 0; rt < 2; ++rt)
        #pragma unroll
        for (int ct = 0; ct < 2; ++ct) {
            #pragma unroll
            for (int r = 0; r < 4; ++r) {
                const float wgt = __expf(lacc[rt][ct][r]);
                const float vp  = bf2f(v_us[rt][ct][r]) + pos[rt][ct][r];
                res_p[ct] += wgt * vp;
                s_p[ct]   += wgt;
            }
        }
        __syncthreads();
    }

    #pragma unroll
    for (int ct = 0; ct < 2; ++ct) {
        #pragma unroll
        for (int off = 16; off < 64; off <<= 1) {
            res_p[ct] += __shfl_xor(res_p[ct], off, 64);
            s_p[ct]   += __shfl_xor(s_p[ct], off, 64);
        }
    }
    if (lg == 0) {
        #pragma unroll
        for (int ct = 0; ct < 2; ++ct) {
            const int d = (ct0 + ct)*16 + lr;
            sRed[(rb2*2+0)*128 + d] = res_p[ct];
            sRed[(rb2*2+1)*128 + d] = s_p[ct];
        }
    }
    __syncthreads();
    if (t < D_) {
        const float rsum = sRed[t]       + sRed[2*128 + t];
        const float ssum = sRed[128 + t] + sRed[3*128 + t];
        float fres = graw[row*D_ + t];
        if (use_stats) fres = bn_apply(fres, stats_in, gam_in, bet_in, t);
        const float val = rsum / ssum + fres;
        gout[row*D_ + t] = val;
        atomicAdd(&stats_out[t], val);
        atomicAdd(&stats_out[128 + t], val*val);
    }
}

// ---------------- elementwise MLP: 1 row/block ----------------
__global__ __launch_bounds__(128) void em_kernel(const float* __restrict__ graw,
    const float* __restrict__ stats_in, const float* __restrict__ gam_in, const float* __restrict__ bet_in,
    const float* __restrict__ W1, const float* __restrict__ b1,
    const float* __restrict__ W2, const float* __restrict__ b2,
    float* __restrict__ gout, float* __restrict__ stats_out)
{
    __shared__ float row[D_], y1[D_];
    const int r = blockIdx.x, d = threadIdx.x;
    const float fn = bn_apply(graw[r*D_ + d], stats_in, gam_in, bet_in, d);
    row[d] = fn;
    __syncthreads();
    float a = b1[d];
    #pragma unroll 4
    for (int e4 = 0; e4 < D_/4; ++e4) {
        float4 w = *(const float4*)(W1 + d*D_ + e4*4);
        float4 x = *(const float4*)&row[e4*4];
        a += w.x*x.x + w.y*x.y + w.z*x.z + w.w*x.w;
    }
    y1[d] = fmaxf(a, 0.f);
    __syncthreads();
    float a2 = b2[d];
    #pragma unroll 4
    for (int e4 = 0; e4 < D_/4; ++e4) {
        float4 w = *(const float4*)(W2 + d*D_ + e4*4);
        float4 x = *(const float4*)&y1[e4*4];
        a2 += w.x*x.x + w.y*x.y + w.z*x.z + w.w*x.w;
    }
    const float g2 = fn + fmaxf(a2, 0.f);
    gout[r*D_ + d] = g2;
    atomicAdd(&stats_out[d], g2);
    atomicAdd(&stats_out[128 + d], g2*g2);
}

// ---------------- final head: 2 rows/block ----------------
__global__ __launch_bounds__(256) void final_kernel(const float* __restrict__ graw,
    const float* __restrict__ stats_in, const float* __restrict__ gam_in, const float* __restrict__ bet_in,
    const float* __restrict__ W1, const float* __restrict__ b1,
    const float* __restrict__ W2, const float* __restrict__ b2,
    float* __restrict__ e_ws)
{
    __shared__ float rows[2][D_];
    __shared__ float h1[2][LAT_];
    const int r0 = blockIdx.x*2, t = threadIdx.x;
    {
        const int rr = t >> 7, d = t & 127;
        rows[rr][d] = bn_apply(graw[(r0+rr)*D_ + d], stats_in, gam_in, bet_in, d);
    }
    __syncthreads();
    float a[2] = {b1[t], b1[t]};
    #pragma unroll 4
    for (int e4 = 0; e4 < D_/4; ++e4) {
        float4 w = *(const float4*)(W1 + t*D_ + e4*4);
        #pragma unroll
        for (int rr = 0; rr < 2; ++rr) {
            float4 x = *(const float4*)&rows[rr][e4*4];
            a[rr] += w.x*x.x + w.y*x.y + w.z*x.z + w.w*x.w;
        }
    }
    #pragma unroll
    for (int rr = 0; rr < 2; ++rr) h1[rr][t] = fmaxf(a[rr], 0.f);
    __syncthreads();
    float a2[2] = {b2[t], b2[t]};
    #pragma unroll 4
    for (int e4 = 0; e4 < LAT_/4; ++e4) {
        float4 w = *(const float4*)(W2 + t*LAT_ + e4*4);
        #pragma unroll
        for (int rr = 0; rr < 2; ++rr) {
            float4 x = *(const float4*)&h1[rr][e4*4];
            a2[rr] += w.x*x.x + w.y*x.y + w.z*x.z + w.w*x.w;
        }
    }
    #pragma unroll
    for (int rr = 0; rr < 2; ++rr) e_ws[(r0+rr)*LAT_ + t] = a2[rr];
}

// ---------------- max over points ----------------
__global__ __launch_bounds__(256) void maxred_kernel(const float* __restrict__ e_ws,
                                                     float* __restrict__ out)
{
    int b = blockIdx.x, l = threadIdx.x;
    float m = -INFINITY;
    #pragma unroll 8
    for (int n=0;n<N_;n++) m = fmaxf(m, e_ws[(b*N_+n)*LAT_+l]);
    out[b*LAT_+l] = m;
}

extern "C" void kernel_launch(void* const* d_in, const int* in_sizes, int n_in,
                              void* d_out, int out_size, void* d_ws, size_t ws_size,
                              hipStream_t stream) {
    (void)in_sizes; (void)n_in; (void)out_size; (void)ws_size;
    const float* xyz    = (const float*)d_in[0];
    const float* feats  = (const float*)d_in[1];
    const float* enc_W  = (const float*)d_in[2];
    const float* enc_b  = (const float*)d_in[3];
    const float* tb_Wq  = (const float*)d_in[4];
    const float* tb_Wk  = (const float*)d_in[5];
    const float* tb_Wv  = (const float*)d_in[6];
    const float* tb_Wg1 = (const float*)d_in[7];
    const float* tb_bg1 = (const float*)d_in[8];
    const float* tb_Wg2 = (const float*)d_in[9];
    const float* tb_bg2 = (const float*)d_in[10];
    const float* tb_Wpe = (const float*)d_in[11];
    const float* tb_bpe = (const float*)d_in[12];
    const float* tb_gamma = (const float*)d_in[13];
    const float* tb_beta  = (const float*)d_in[14];
    const float* em_W1  = (const float*)d_in[15];
    const float* em_b1  = (const float*)d_in[16];
    const float* em_W2  = (const float*)d_in[17];
    const float* em_b2  = (const float*)d_in[18];
    const float* em_gamma = (const float*)d_in[19];
    const float* em_beta  = (const float*)d_in[20];
    const float* fcf_W1 = (const float*)d_in[21];
    const float* fcf_b1 = (const float*)d_in[22];
    const float* fcf_W2 = (const float*)d_in[23];
    const float* fcf_b2 = (const float*)d_in[24];
    float* out = (float*)d_out;

    // workspace layout
    float* ws   = (float*)d_ws;
    float* buf0 = ws;                      // ROWS_*D_  f32
    float* buf1 = buf0 + ROWS_*D_;         // ROWS_*D_  f32
    float* hbb  = buf1 + ROWS_*D_;         // ROWS_*D_  f32
    float* ebuf = hbb  + ROWS_*D_;         // ROWS_*LAT_ f32
    float* psi  = ebuf + ROWS_*LAT_;       // 3*128*34 f32
    float* wqg  = psi  + 3*D_*34;          // 3*128*128 f32
    float* wkg  = wqg  + 3*D_*D_;          // 3*128*128 f32
    float* stats = wkg + 3*D_*D_;          // 5 x 256 f32
    float* sA0 = stats;
    float* sA1 = stats + 256;
    float* sE1 = stats + 512;
    float* sA2 = stats + 768;
    float* sE2 = stats + 1024;
    unsigned short* kwbuf = (unsigned short*)(stats + 5*256);      // ROWS_*D_ bf16
    unsigned short* vbuf  = kwbuf + ROWS_*D_;                      // ROWS_*D_ bf16
    unsigned short* gF    = vbuf + ROWS_*D_;                       // ROWS_*64 bf16

    hipMemsetAsync(stats, 0, 5*256*sizeof(float), stream);

    prep_kernel<<<PB_WQG, 256, 0, stream>>>(xyz, feats, enc_W, enc_b,
        tb_Wg1, tb_Wpe, tb_bpe, tb_Wq, tb_Wk, gF, psi, wqg, wkg, buf0);

    const float* gz = tb_gamma;  // dummies for unused-stats calls
    // Layer 0
    qkv3_kernel<<<ROWS_, 128, 0, stream>>>(buf0, gz, gz, gz, 0,
        tb_Wv, wqg, wkg, tb_bg1, hbb, kwbuf, vbuf);
    attn_mfma_kernel<<<ROWS_, 512, 0, stream>>>(xyz, buf0, gz, gz, gz, 0,
        hbb, kwbuf, vbuf, gF, psi,
        tb_Wpe, tb_bpe, tb_Wg2, tb_bg2, buf1, sA0);
    // Layer 1
    qkv3_kernel<<<ROWS_, 128, 0, stream>>>(buf1, sA0, tb_gamma, tb_beta, 1,
        tb_Wv + 1*D_*D_, wqg + 1*D_*D_, wkg + 1*D_*D_, tb_bg1 + 1*D_, hbb, kwbuf, vbuf);
    attn_mfma_kernel<<<ROWS_, 512, 0, stream>>>(xyz, buf1, sA0, tb_gamma, tb_beta, 1,
        hbb, kwbuf, vbuf, gF, psi + 1*D_*34,
        tb_Wpe + 1*D_*NPOS_, tb_bpe + 1*D_, tb_Wg2 + 1*D_*D_, tb_bg2 + 1*D_, buf0, sA1);
    em_kernel<<<ROWS_, 128, 0, stream>>>(buf0, sA1, tb_gamma + 1*D_, tb_beta + 1*D_,
                                         em_W1, em_b1, em_W2, em_b2, buf1, sE1);
    // Layer 2
    qkv3_kernel<<<ROWS_, 128, 0, stream>>>(buf1, sE1, em_gamma, em_beta, 1,
        tb_Wv + 2*D_*D_, wqg + 2*D_*D_, wkg + 2*D_*D_, tb_bg1 + 2*D_, hbb, kwbuf, vbuf);
    attn_mfma_kernel<<<ROWS_, 512, 0, stream>>>(xyz, buf1, sE1, em_gamma, em_beta, 1,
        hbb, kwbuf, vbuf, gF, psi + 2*D_*34,
        tb_Wpe + 2*D_*NPOS_, tb_bpe + 2*D_, tb_Wg2 + 2*D_*D_, tb_bg2 + 2*D_, buf0, sA2);
    em_kernel<<<ROWS_, 128, 0, stream>>>(buf0, sA2, tb_gamma + 2*D_, tb_beta + 2*D_,
                                         em_W1 + 1*D_*D_, em_b1 + 1*D_,
                                         em_W2 + 1*D_*D_, em_b2 + 1*D_, buf1, sE2);
    // Head
    final_kernel<<<ROWS_/2, 256, 0, stream>>>(buf1, sE2, em_gamma + 1*D_, em_beta + 1*D_,
                                              fcf_W1, fcf_b1, fcf_W2, fcf_b2, ebuf);
    maxred_kernel<<<B_, 256, 0, stream>>>(ebuf, out);
}